// Round 16
// baseline (703.829 us; speedup 1.0000x reference)
//
#include <hip/hip_runtime.h>

// ---------------------------------------------------------------------------
// MultiEdgeClassifier: 6-layer GCN + BN + weighted residual + edge-pair FC
// N=100k nodes, HID=128, E=1.6M edges (+N self loops), E_OUT=400k
// Round 15: fold pass eliminated — static compressed edge records
//           (src:17|norm_bf14:14|flag:1) written once by norm_kernel;
//           SpMM applies hscale[src] inline via SCALAR loads (stream is
//           scalarized since R13, so this costs s_load + 1 v_mul, not the
//           per-lane VMEM that killed R8).
// ---------------------------------------------------------------------------

#define NW 8192      // waves for spmm (2048 blocks x 4)
#define BKT 128      // dsts per bucket
#define CAP 6144     // max edges per bucket staged in LDS (mean ~2175)

typedef __attribute__((ext_vector_type(8))) short short8;
typedef __attribute__((ext_vector_type(4))) float f32x4;

static __device__ __forceinline__ unsigned short f2bf(float f) {
  unsigned u = __float_as_uint(f);
  u = u + 0x7fffu + ((u >> 16) & 1u);   // RNE
  return (unsigned short)(u >> 16);
}
static __device__ __forceinline__ float bf2f_lo(unsigned v) {
  return __uint_as_float(v << 16);
}
static __device__ __forceinline__ float bf2f_hi(unsigned v) {
  return __uint_as_float(v & 0xffff0000u);
}
static __device__ __forceinline__ unsigned pack_bf2(float a, float b) {
  return (unsigned)f2bf(a) | ((unsigned)f2bf(b) << 16);
}
static __device__ __forceinline__ unsigned rfl(unsigned v) {
  return (unsigned)__builtin_amdgcn_readfirstlane((int)v);
}

// ---------------- preprocessing: two-level radix sort by dst ----------------

__global__ __launch_bounds__(256) void hist_bucket_kernel(const int* __restrict__ dst,
                                                          int* __restrict__ bcnt,
                                                          int e, int n, int nbk) {
  __shared__ int h[1024];
  int T = e + n;
  int chunk = (T + gridDim.x - 1) / gridDim.x;
  int j0 = blockIdx.x * chunk;
  int j1 = min(j0 + chunk, T);
  for (int i = threadIdx.x; i < nbk; i += 256) h[i] = 0;
  __syncthreads();
  for (int j = j0 + threadIdx.x; j < j1; j += 256) {
    int d = (j < e) ? dst[j] : (j - e);
    atomicAdd(&h[d >> 7], 1);
  }
  __syncthreads();
  for (int i = threadIdx.x; i < nbk; i += 256)
    if (h[i]) atomicAdd(&bcnt[i], h[i]);
}

__global__ __launch_bounds__(1024) void scan_buckets_kernel(const int* __restrict__ bcnt,
                                                            int* __restrict__ bbase,
                                                            int nbk, int total) {
  __shared__ int lds[1024];
  int t = threadIdx.x;
  int v = (t < nbk) ? bcnt[t] : 0;
  int val = v;
  lds[t] = val; __syncthreads();
  for (int off = 1; off < 1024; off <<= 1) {
    int x = (t >= off) ? lds[t - off] : 0;
    __syncthreads();
    val += x;
    lds[t] = val;
    __syncthreads();
  }
  if (t < nbk) bbase[t] = val - v;
  if (t == 0) bbase[nbk] = total;
}

__global__ __launch_bounds__(256) void scatter_bucket_kernel(const int* __restrict__ src,
                                                             const int* __restrict__ dst,
                                                             int* __restrict__ bfill,
                                                             int2* __restrict__ ebuf,
                                                             int e, int n, int nbk) {
  __shared__ int cntL[1024], baseL[1024];
  int T = e + n;
  int chunk = (T + gridDim.x - 1) / gridDim.x;
  int j0 = blockIdx.x * chunk;
  int j1 = min(j0 + chunk, T);
  for (int i = threadIdx.x; i < nbk; i += 256) cntL[i] = 0;
  __syncthreads();
  for (int j = j0 + threadIdx.x; j < j1; j += 256) {
    int d = (j < e) ? dst[j] : (j - e);
    atomicAdd(&cntL[d >> 7], 1);
  }
  __syncthreads();
  for (int i = threadIdx.x; i < nbk; i += 256) {
    int c = cntL[i];
    baseL[i] = c ? atomicAdd(&bfill[i], c) : 0;
    cntL[i] = 0;
  }
  __syncthreads();
  for (int j = j0 + threadIdx.x; j < j1; j += 256) {
    int s, d;
    if (j < e) { s = src[j]; d = dst[j]; } else { s = j - e; d = s; }
    int b = d >> 7;
    int r = atomicAdd(&cntL[b], 1);
    ebuf[baseL[b] + r] = make_int2(s, d);
  }
}

// pass C: in-LDS sort of each bucket by dst; emits rs, dis, sorted (src,dst)
__global__ __launch_bounds__(256) void sort_bucket_kernel(const int* __restrict__ bbase,
                                                          const int2* __restrict__ ebuf,
                                                          int2* __restrict__ ebuf2,
                                                          int* __restrict__ rs,
                                                          float* __restrict__ dis,
                                                          int n, int total) {
  __shared__ int2 el[CAP];
  __shared__ int hist[BKT], excl[BKT], cur[BKT], scn[BKT];
  int b = blockIdx.x, t = threadIdx.x;
  int e0 = bbase[b], e1 = bbase[b + 1];
  int sz = e1 - e0;
  bool inl = (sz <= CAP);
  if (inl)
    for (int i = t; i < sz; i += 256) el[i] = ebuf[e0 + i];
  if (t < BKT) hist[t] = 0;
  __syncthreads();
  for (int i = t; i < sz; i += 256) {
    int d = inl ? el[i].y : ebuf[e0 + i].y;
    atomicAdd(&hist[d & (BKT - 1)], 1);
  }
  __syncthreads();
  int val = (t < BKT) ? hist[t] : 0;
  if (t < BKT) scn[t] = val;
  __syncthreads();
  for (int off = 1; off < BKT; off <<= 1) {
    int x = (t >= off && t < BKT) ? scn[t - off] : 0;
    __syncthreads();
    if (t < BKT) { val += x; scn[t] = val; }
    __syncthreads();
  }
  if (t < BKT) {
    int ex = val - hist[t];
    excl[t] = ex;
    cur[t] = 0;
    int d = (b << 7) + t;
    if (d < n) {
      rs[d] = e0 + ex;
      dis[d] = rsqrtf((float)hist[t]);  // deg >= 1 (self-loop)
    }
  }
  if (b == 0 && t == 0) rs[n] = total;
  __syncthreads();
  for (int i = t; i < sz; i += 256) {
    int2 p = inl ? el[i] : ebuf[e0 + i];
    int dl = p.y & (BKT - 1);
    int pos = atomicAdd(&cur[dl], 1);
    ebuf2[e0 + excl[dl] + pos] = p;
  }
}

// pass D: (src,dst) -> compressed static record (src:17 | norm_bf14:14 | flag:1)
__global__ void norm_kernel(const int2* __restrict__ ebuf2, const float* __restrict__ dis,
                            unsigned* __restrict__ esnc, int T) {
  int j = blockIdx.x * blockDim.x + threadIdx.x;
  if (j >= T) return;
  int2 p = ebuf2[j];
  float nm = dis[p.x] * dis[p.y];
  unsigned fb = __float_as_uint(nm) + 0x10000u;      // RNE on bit 17
  unsigned field = (fb >> 17) & 0x3fffu;             // exp8 + mant6
  unsigned flag = (j + 1 == T || ebuf2[j + 1].y != p.y) ? 1u : 0u;
  esnc[j] = ((unsigned)p.x << 15) | (field << 1) | flag;
}

__global__ void wave_bounds_kernel(const int* __restrict__ rs, int* __restrict__ A,
                                   int n, int nw, int eb) {
  int w = blockIdx.x * blockDim.x + threadIdx.x;
  if (w > nw) return;
  int target = w * eb;
  int lo = 0, hi = n;
  while (lo < hi) {
    int mid = (lo + hi) >> 1;
    if (rs[mid] < target) lo = mid + 1; else hi = mid;
  }
  A[w] = lo;
}

__global__ void softmax_w_kernel(const float* __restrict__ lw, float* __restrict__ w, int l) {
  if (threadIdx.x == 0 && blockIdx.x == 0) {
    float m = lw[0];
    for (int i = 1; i < l; ++i) m = fmaxf(m, lw[i]);
    float s = 0.f;
    for (int i = 0; i < l; ++i) s += expf(lw[i] - m);
    for (int i = 0; i < l; ++i) w[i] = expf(lw[i] - m) / s;
  }
}

__global__ void transpose_w_kernel(const float* __restrict__ W, unsigned short* __restrict__ Wt,
                                   int total) {
  int t = blockIdx.x * blockDim.x + threadIdx.x;
  if (t >= total) return;
  int l = t >> 14;
  int nc = (t >> 7) & 127;
  int kk = t & 127;
  Wt[t] = f2bf(W[(size_t)l * 16384 + kk * 128 + nc]);
}

// ---------------- embed: register-W, LDS-staged x, bf16 output ----------------

__global__ __launch_bounds__(256) void embed_kernel(const float* __restrict__ x,
                                                    const float* __restrict__ W,
                                                    const float* __restrict__ b,
                                                    unsigned short* __restrict__ xe16, int n) {
  __shared__ float xs[64][20];
  int tid = threadIdx.x;
  int c = tid & 127, half = tid >> 7;
  float wreg[16];
#pragma unroll
  for (int k = 0; k < 16; ++k) wreg[k] = W[k * 128 + c];
  float bc = b[c];
  int ntile = (n + 63) >> 6;
  for (int t = blockIdx.x; t < ntile; t += gridDim.x) {
    int row0 = t * 64;
    {
      int r = tid >> 2, q = tid & 3;
      int row = row0 + r;
      float4 v = (row < n) ? *(const float4*)(x + (size_t)row * 16 + q * 4)
                           : make_float4(0.f, 0.f, 0.f, 0.f);
      *(float4*)&xs[r][q * 4] = v;
    }
    __syncthreads();
    int rbase = half * 32;
    for (int rr = 0; rr < 32; ++rr) {
      int row = row0 + rbase + rr;
      if (row >= n) break;
      float acc = bc;
#pragma unroll
      for (int k = 0; k < 16; ++k) acc = fmaf(xs[rbase + rr][k], wreg[k], acc);
      xe16[(size_t)row * 128 + c] = f2bf(acc);
    }
    __syncthreads();
  }
}

// ---------------- fused (BN+ReLU+residual of prev layer) + MFMA GEMM ----------------

#define EPS 132   // padded LDS row stride (bf16 elems)

template<bool HASBN>
__global__ __launch_bounds__(256) void gemm_fused_kernel(
    const unsigned* __restrict__ aggbf,       // HASBN: packed bf16x2 agg (prev layer)
    const float* __restrict__ stats8,         // HASBN: 8 slices x 256 (prev layer)
    const float* __restrict__ gamma, const float* __restrict__ beta,
    const float* __restrict__ wsm, int layer, // prev layer idx
    unsigned* __restrict__ xe16,              // packed bf16x2 residual accumulator
    const unsigned short* __restrict__ Wt,
    unsigned char* __restrict__ Hq,           // int8 h table, 128 B/row
    float* __restrict__ hscale, int n) {      // per-row dequant scale
  __shared__ short8 wlds[2048];               // 32 KB
  __shared__ unsigned short ep[64 * EPS];     // 16.5 KB epilogue pack buffer
  __shared__ float sc_s[128], sh_s[128];
  int tid = threadIdx.x;
  const short* WtS = (const short*)Wt;
#pragma unroll
  for (int it = 0; it < 8; ++it) {
    int s = it * 256 + tid;
    int ln = s & 63, g = s >> 6;              // g = n0*4+ks
    int col = ((g >> 2) << 4) + (ln & 15);
    wlds[s] = *(const short8*)(WtS + (size_t)col * 128 + (g & 3) * 32 + (ln >> 4) * 8);
  }
  if (HASBN && tid < 128) {
    float s = 0.f, q = 0.f;
#pragma unroll
    for (int k = 0; k < 8; ++k) {
      s += stats8[k * 256 + tid];
      q += stats8[k * 256 + 128 + tid];
    }
    float invn = 1.f / (float)n;
    float mean = s * invn;
    float var = q * invn - mean * mean;
    float sc = gamma[tid] * rsqrtf(var + 1e-5f);
    sc_s[tid] = sc;
    sh_s[tid] = beta[tid] - mean * sc;
  }
  __syncthreads();

  int wid = tid >> 6, lane = tid & 63;
  int lrow = lane & 15, lk = lane >> 4;
  float wres = HASBN ? wsm[layer] : 0.f;

  int ntiles = (n + 63) >> 6;
  for (int tile = blockIdx.x; tile < ntiles; tile += gridDim.x) {
    int row = tile * 64 + wid * 16 + lrow;
    short8 afrag[4];
    if (row < n) {
      if (HASBN) {
        const unsigned* arow = aggbf + (size_t)row * 64;
        unsigned* xrow = xe16 + (size_t)row * 64;
#pragma unroll
        for (int ks = 0; ks < 4; ++ks) {
          int c0 = ks * 32 + lk * 8;          // first channel (8 channels = 4 words)
          uint4 av = *(const uint4*)(arow + (c0 >> 1));
          uint4 xw = *(const uint4*)(xrow + (c0 >> 1));
          unsigned aw[4] = {av.x, av.y, av.z, av.w};
          unsigned xv[4] = {xw.x, xw.y, xw.z, xw.w};
          unsigned xo[4];
          short8 af;
#pragma unroll
          for (int d = 0; d < 4; ++d) {
            int c = c0 + 2 * d;
            float v0 = fmaxf(fmaf(bf2f_lo(aw[d]), sc_s[c], sh_s[c]), 0.f);
            float v1 = fmaxf(fmaf(bf2f_hi(aw[d]), sc_s[c + 1], sh_s[c + 1]), 0.f);
            float xn0 = fmaf(wres, v0, bf2f_lo(xv[d]));
            float xn1 = fmaf(wres, v1, bf2f_hi(xv[d]));
            unsigned pw = pack_bf2(xn0, xn1);
            xo[d] = pw;
            af[2 * d]     = (short)(pw & 0xffff);
            af[2 * d + 1] = (short)(pw >> 16);
          }
          *(uint4*)(xrow + (c0 >> 1)) = make_uint4(xo[0], xo[1], xo[2], xo[3]);
          afrag[ks] = af;
        }
      } else {
        const short* AS = (const short*)xe16;
#pragma unroll
        for (int ks = 0; ks < 4; ++ks)
          afrag[ks] = *(const short8*)(AS + (size_t)row * 128 + ks * 32 + lk * 8);
      }
    } else {
#pragma unroll
      for (int ks = 0; ks < 4; ++ks) afrag[ks] = (short8)0;
    }
    f32x4 acc[8];
#pragma unroll
    for (int n0 = 0; n0 < 8; ++n0) acc[n0] = (f32x4)0.f;
#pragma unroll
    for (int ks = 0; ks < 4; ++ks)
#pragma unroll
      for (int n0 = 0; n0 < 8; ++n0)
        acc[n0] = __builtin_amdgcn_mfma_f32_16x16x32_bf16(
            afrag[ks], wlds[(n0 * 4 + ks) * 64 + lane], acc[n0], 0, 0, 0);

    // ---- epilogue: pack to LDS, per-row int8 quantization, coalesced store ----
    int eprow0 = wid * 16 + lk * 4;           // row within 64-row tile
#pragma unroll
    for (int n0 = 0; n0 < 8; ++n0) {
      int col = n0 * 16 + lrow;
#pragma unroll
      for (int r = 0; r < 4; ++r)
        ep[(eprow0 + r) * EPS + col] = f2bf(acc[n0][r]);
    }
    __syncthreads();
    int trow = tid >> 2;                      // 0..63
    int tchunk = tid & 3;                     // 32 channels per thread
    int orow = tile * 64 + trow;
    const unsigned short* srcl = ep + trow * EPS + tchunk * 32;
    float vals[32];
    float mx = 0.f;
#pragma unroll
    for (int c = 0; c < 4; ++c) {
      short8 ch = *(const short8*)(srcl + c * 8);
#pragma unroll
      for (int i = 0; i < 8; ++i) {
        float v = __uint_as_float(((unsigned)(unsigned short)ch[i]) << 16);
        vals[c * 8 + i] = v;
        mx = fmaxf(mx, __builtin_fabsf(v));
      }
    }
    mx = fmaxf(mx, __shfl_xor(mx, 1));        // 4 lanes of one row
    mx = fmaxf(mx, __shfl_xor(mx, 2));
    float inv = (mx > 0.f) ? 127.f / mx : 0.f;
    if (orow < n) {
      if (tchunk == 0) hscale[orow] = mx * (1.f / 127.f);
      unsigned q[8];
#pragma unroll
      for (int d = 0; d < 8; ++d) {
        unsigned b = 0;
#pragma unroll
        for (int j = 0; j < 4; ++j) {
          int qi = (int)rintf(vals[d * 4 + j] * inv);
          b |= ((unsigned)(qi & 0xff)) << (8 * j);
        }
        q[d] = b;
      }
      uint4* dst = (uint4*)(Hq + (size_t)orow * 128 + tchunk * 32);
      dst[0] = make_uint4(q[0], q[1], q[2], q[3]);
      dst[1] = make_uint4(q[4], q[5], q[6], q[7]);
    }
    __syncthreads();
  }
}

// ---------------- flag-stream segmented SpMM (int8, inline scalar scale) ----------------
// Static record (wave-uniform): src:17 | norm_bf14:14 | flag:1.
// Scale applied inline: sc = hscale[src] via SCALAR load (SGPR address).

#define SPMM_STEP(SW, SC, VI)                                              \
  {                                                                        \
    float fac = __uint_as_float(((SW) & 0x7ffeu) << 16) * (SC);            \
    a0 = fmaf(fac, (float)(signed char)((VI) & 0xff), a0);                 \
    a1 = fmaf(fac, (float)(signed char)((VI) >> 8), a1);                   \
    if ((SW) & 1u) {                                                       \
      aggbf[(size_t)row * 64 + lane] = pack_bf2(a0, a1);                   \
      t0 += a0; t1 += a1;                                                  \
      u0 = fmaf(a0, a0, u0); u1 = fmaf(a1, a1, u1);                        \
      a0 = 0.f; a1 = 0.f;                                                  \
      ++row;                                                               \
    }                                                                      \
  }

#define SPMM_GATHER(SW) (*(const unsigned short*)(hqb + (((SW) >> 8) & ~127u) + lane2))
#define SPMM_SCALE(SW)  (hscale[(SW) >> 15])

__global__ __launch_bounds__(256) void spmm_kernel(
    const int* __restrict__ rs, const int* __restrict__ A,
    const unsigned* __restrict__ esnc, const unsigned char* __restrict__ hq,
    const float* __restrict__ hscale,
    unsigned* __restrict__ aggbf, float* __restrict__ stats8, int n) {
  int tid = threadIdx.x;
  int wid = tid >> 6, lane = tid & 63;
  int lane2 = lane * 2;                      // byte offset within 128B row
  const char* hqb = (const char*)hq;
  int w = blockIdx.x * 4 + wid;
  int row = __builtin_amdgcn_readfirstlane(A[w]);
  int row_end = __builtin_amdgcn_readfirstlane(A[w + 1]);
  float t0 = 0.f, t1 = 0.f, u0 = 0.f, u1 = 0.f;
  if (row < row_end) {
    int e = __builtin_amdgcn_readfirstlane(rs[row]);
    int eend = __builtin_amdgcn_readfirstlane(rs[row_end]);
    float a0 = 0.f, a1 = 0.f;
    while ((e & 3) && e < eend) {              // peel to 16B alignment
      unsigned sw = rfl(esnc[e]);
      float sc = SPMM_SCALE(sw);
      unsigned v = SPMM_GATHER(sw);
      SPMM_STEP(sw, sc, v)
      ++e;
    }
    const uint4* e4 = (const uint4*)(esnc + e);
    int nq = (eend - e) >> 2;
    int i4 = 0;
    while (i4 + 2 <= nq) {                     // 8 edges per iter
      uint4 qa = e4[i4], qb = e4[i4 + 1];
      unsigned w0 = rfl(qa.x), w1 = rfl(qa.y), w2 = rfl(qa.z), w3 = rfl(qa.w);
      unsigned w4 = rfl(qb.x), w5 = rfl(qb.y), w6 = rfl(qb.z), w7 = rfl(qb.w);
      float c0 = SPMM_SCALE(w0), c1 = SPMM_SCALE(w1);
      float c2 = SPMM_SCALE(w2), c3 = SPMM_SCALE(w3);
      float c4 = SPMM_SCALE(w4), c5 = SPMM_SCALE(w5);
      float c6 = SPMM_SCALE(w6), c7 = SPMM_SCALE(w7);
      unsigned v0 = SPMM_GATHER(w0);
      unsigned v1 = SPMM_GATHER(w1);
      unsigned v2 = SPMM_GATHER(w2);
      unsigned v3 = SPMM_GATHER(w3);
      unsigned v4 = SPMM_GATHER(w4);
      unsigned v5 = SPMM_GATHER(w5);
      unsigned v6 = SPMM_GATHER(w6);
      unsigned v7 = SPMM_GATHER(w7);
      SPMM_STEP(w0, c0, v0) SPMM_STEP(w1, c1, v1)
      SPMM_STEP(w2, c2, v2) SPMM_STEP(w3, c3, v3)
      SPMM_STEP(w4, c4, v4) SPMM_STEP(w5, c5, v5)
      SPMM_STEP(w6, c6, v6) SPMM_STEP(w7, c7, v7)
      i4 += 2;
    }
    e += i4 << 2;
    while (e < eend) {
      unsigned sw = rfl(esnc[e]);
      float sc = SPMM_SCALE(sw);
      unsigned v = SPMM_GATHER(sw);
      SPMM_STEP(sw, sc, v)
      ++e;
    }
  }
  __shared__ float red[4][256];
  red[0][tid] = t0; red[1][tid] = t1; red[2][tid] = u0; red[3][tid] = u1;
  __syncthreads();
  float v = red[wid][lane] + red[wid][64 + lane] + red[wid][128 + lane] + red[wid][192 + lane];
  int c = (wid == 0) ? (2 * lane) : (wid == 1) ? (2 * lane + 1)
        : (wid == 2) ? (128 + 2 * lane) : (129 + 2 * lane);
  atomicAdd(&stats8[(blockIdx.x & 7) * 256 + c], v);
}

// ---------------- final FC (fused BN of last layer; bf16 xe) ----------------

__global__ __launch_bounds__(256) void fc_node_kernel(
    const unsigned* __restrict__ aggbf, const float* __restrict__ stats8,
    const float* __restrict__ gamma, const float* __restrict__ beta,
    const float* __restrict__ wsm, int layer,
    const unsigned* __restrict__ xe16, const float* __restrict__ fcW,
    float* __restrict__ y, int n) {
  __shared__ float sc_s[128], sh_s[128];
  int tid = threadIdx.x;
  if (tid < 128) {
    float s = 0.f, q = 0.f;
#pragma unroll
    for (int k = 0; k < 8; ++k) {
      s += stats8[k * 256 + tid];
      q += stats8[k * 256 + 128 + tid];
    }
    float invn = 1.f / (float)n;
    float mean = s * invn;
    float var = q * invn - mean * mean;
    float sc = gamma[tid] * rsqrtf(var + 1e-5f);
    sc_s[tid] = sc;
    sh_s[tid] = beta[tid] - mean * sc;
  }
  __syncthreads();
  int wid = tid >> 6, lane = tid & 63;
  int r = blockIdx.x * 4 + wid;
  if (r >= n) return;
  float w = wsm[layer];
  unsigned av = aggbf[(size_t)r * 64 + lane];
  unsigned xv = xe16[(size_t)r * 64 + lane];
  int c0 = lane * 2, c1 = c0 + 1;
  float x0 = fmaf(w, fmaxf(fmaf(bf2f_lo(av), sc_s[c0], sh_s[c0]), 0.f), bf2f_lo(xv));
  float x1 = fmaf(w, fmaxf(fmaf(bf2f_hi(av), sc_s[c1], sh_s[c1]), 0.f), bf2f_hi(xv));
  float a00 = x0 * fcW[c0 * 2 + 0] + x1 * fcW[c1 * 2 + 0];
  float a01 = x0 * fcW[c0 * 2 + 1] + x1 * fcW[c1 * 2 + 1];
  float a10 = x0 * fcW[(128 + c0) * 2 + 0] + x1 * fcW[(128 + c1) * 2 + 0];
  float a11 = x0 * fcW[(128 + c0) * 2 + 1] + x1 * fcW[(128 + c1) * 2 + 1];
#pragma unroll
  for (int off = 32; off; off >>= 1) {
    a00 += __shfl_down(a00, off);
    a01 += __shfl_down(a01, off);
    a10 += __shfl_down(a10, off);
    a11 += __shfl_down(a11, off);
  }
  if (lane == 0) *(float4*)(y + (size_t)r * 4) = make_float4(a00, a01, a10, a11);
}

__global__ void edge_out_kernel(const float* __restrict__ y, const int* __restrict__ eo,
                                const float* __restrict__ fcb, float* __restrict__ out, int m) {
  int j = blockIdx.x * blockDim.x + threadIdx.x;
  if (j >= m) return;
  int a = eo[j], b = eo[m + j];
  float4 ya = *(const float4*)(y + (size_t)a * 4);
  float4 yb = *(const float4*)(y + (size_t)b * 4);
  out[(size_t)j * 2 + 0] = ya.x + yb.z + fcb[0];
  out[(size_t)j * 2 + 1] = ya.y + yb.w + fcb[1];
}

// ---------------------------------------------------------------------------

extern "C" void kernel_launch(void* const* d_in, const int* in_sizes, int n_in,
                              void* d_out, int out_size, void* d_ws, size_t ws_size,
                              hipStream_t stream) {
  const float* x     = (const float*)d_in[0];
  const int*   ei    = (const int*)d_in[1];
  const int*   eo    = (const int*)d_in[2];
  const float* embW  = (const float*)d_in[3];
  const float* embB  = (const float*)d_in[4];
  const float* convW = (const float*)d_in[5];
  const float* gamma = (const float*)d_in[7];
  const float* beta  = (const float*)d_in[8];
  const float* lw    = (const float*)d_in[9];
  const float* fcW   = (const float*)d_in[10];
  const float* fcb   = (const float*)d_in[11];
  float* out = (float*)d_out;

  const int n = in_sizes[0] / 16;          // 100000
  const int e = in_sizes[1] / 2;           // 1600000
  const int m = in_sizes[2] / 2;           // 400000
  const int L = in_sizes[5] / (128 * 128); // 6

  const int T   = e + n;                   // total edges incl self loops
  const int EB  = (T + NW - 1) / NW;       // edges per wave target
  const int nbk = (n + BKT - 1) / BKT;     // 782 buckets

  const int* esrc = ei;
  const int* edst = ei + e;

  char* wsp = (char*)d_ws;
  size_t off = 0;
  auto take = [&](size_t bytes) -> void* {
    void* p = wsp + off;
    off = (off + bytes + 255) & ~(size_t)255;
    return p;
  };
  int*            bcnt     = (int*)take((size_t)(nbk + 1) * 4);
  int*            bbase    = (int*)take((size_t)(nbk + 1) * 4);
  int*            bfill    = (int*)take((size_t)(nbk + 1) * 4);
  int*            rs       = (int*)take((size_t)(n + 1) * 4);
  float*          dis      = (float*)take((size_t)n * 4);
  float*          hscale   = (float*)take((size_t)n * 4);
  float*          wsm      = (float*)take(64 * 4);
  float*          stats    = (float*)take((size_t)L * 8 * 256 * 4);
  int*            A        = (int*)take((size_t)(NW + 1) * 4);
  int2*           ebuf     = (int2*)take((size_t)T * 8);   // bucketed (src,dst)
  int2*           ebuf2    = (int2*)take((size_t)T * 8);   // sorted (src,dst)
  unsigned*       esnc     = (unsigned*)take((size_t)T * 4); // static compressed records
  unsigned short* xe16     = (unsigned short*)take((size_t)n * 128 * 2);
  unsigned char*  hq       = (unsigned char*)take((size_t)n * 128);
  unsigned*       aggbf    = (unsigned*)take((size_t)n * 64 * 4);
  unsigned short* Wt       = (unsigned short*)take((size_t)L * 128 * 128 * 2);
  float*          y        = (float*)take((size_t)n * 4 * 4);
  if (off > ws_size || nbk > 1024) return;

  // --- preprocessing: radix sort by dst ---
  hipMemsetAsync(bcnt, 0, (size_t)(nbk + 1) * 4, stream);
  hipMemsetAsync(stats, 0, (size_t)L * 8 * 256 * 4, stream);
  hist_bucket_kernel<<<512, 256, 0, stream>>>(edst, bcnt, e, n, nbk);
  scan_buckets_kernel<<<1, 1024, 0, stream>>>(bcnt, bbase, nbk, T);
  hipMemcpyAsync(bfill, bbase, (size_t)nbk * 4, hipMemcpyDeviceToDevice, stream);
  scatter_bucket_kernel<<<512, 256, 0, stream>>>(esrc, edst, bfill, ebuf, e, n, nbk);
  sort_bucket_kernel<<<nbk, 256, 0, stream>>>(bbase, ebuf, ebuf2, rs, dis, n, T);
  norm_kernel<<<(T + 255) / 256, 256, 0, stream>>>(ebuf2, dis, esnc, T);
  wave_bounds_kernel<<<(NW + 256) / 256, 256, 0, stream>>>(rs, A, n, NW, EB);
  softmax_w_kernel<<<1, 64, 0, stream>>>(lw, wsm, L);
  transpose_w_kernel<<<(L * 16384 + 255) / 256, 256, 0, stream>>>(convW, Wt, L * 16384);

  // --- embed (bf16 xe) ---
  embed_kernel<<<1024, 256, 0, stream>>>(x, embW, embB, xe16, n);

  // --- 6 GCN layers (conv_b dropped: cancels under BN) ---
  const int ntiles = (n + 63) >> 6;
  const int gemm_grid = (ntiles + 1) / 2;   // exactly <=2 tiles per block
  for (int i = 0; i < L; ++i) {
    if (i == 0) {
      gemm_fused_kernel<false><<<gemm_grid, 256, 0, stream>>>(
          nullptr, nullptr, nullptr, nullptr, wsm, 0, (unsigned*)xe16,
          Wt, hq, hscale, n);
    } else {
      gemm_fused_kernel<true><<<gemm_grid, 256, 0, stream>>>(
          aggbf, stats + (size_t)(i - 1) * 2048,
          gamma + (size_t)(i - 1) * 128, beta + (size_t)(i - 1) * 128, wsm, i - 1,
          (unsigned*)xe16, Wt + (size_t)i * 16384, hq, hscale, n);
    }
    spmm_kernel<<<NW / 4, 256, 0, stream>>>(rs, A, esnc, hq, hscale,
                                            aggbf, stats + (size_t)i * 2048, n);
  }

  // --- final FC (fused BN of layer L-1) ---
  fc_node_kernel<<<(n + 3) / 4, 256, 0, stream>>>(
      aggbf, stats + (size_t)(L - 1) * 2048,
      gamma + (size_t)(L - 1) * 128, beta + (size_t)(L - 1) * 128, wsm, L - 1,
      (const unsigned*)xe16, fcW, y, n);
  edge_out_kernel<<<(m + 255) / 256, 256, 0, stream>>>(y, eo, fcb, out, m);
}

// Round 17
// 590.264 us; speedup vs baseline: 1.1924x; 1.1924x over previous
//
#include <hip/hip_runtime.h>

// ---------------------------------------------------------------------------
// MultiEdgeClassifier: 6-layer GCN + BN + weighted residual + edge-pair FC
// N=100k nodes, HID=128, E=1.6M edges (+N self loops), E_OUT=400k
// Round 16: R14 restored (fold pass with pre-folded scale — R15's inline
//           scalar loads regressed); bucketed scatter records packed to 4B
//           (src:17|dstlocal:7), halving scatter write traffic.
// ---------------------------------------------------------------------------

#define NW 8192      // waves for spmm (2048 blocks x 4)
#define BKT 128      // dsts per bucket
#define CAP 6144     // max edges per bucket staged in LDS (mean ~2175)

typedef __attribute__((ext_vector_type(8))) short short8;
typedef __attribute__((ext_vector_type(4))) float f32x4;

static __device__ __forceinline__ unsigned short f2bf(float f) {
  unsigned u = __float_as_uint(f);
  u = u + 0x7fffu + ((u >> 16) & 1u);   // RNE
  return (unsigned short)(u >> 16);
}
static __device__ __forceinline__ float bf2f_lo(unsigned v) {
  return __uint_as_float(v << 16);
}
static __device__ __forceinline__ float bf2f_hi(unsigned v) {
  return __uint_as_float(v & 0xffff0000u);
}
static __device__ __forceinline__ unsigned pack_bf2(float a, float b) {
  return (unsigned)f2bf(a) | ((unsigned)f2bf(b) << 16);
}
static __device__ __forceinline__ unsigned rfl(unsigned v) {
  return (unsigned)__builtin_amdgcn_readfirstlane((int)v);
}

// ---------------- preprocessing: two-level radix sort by dst ----------------

__global__ __launch_bounds__(256) void hist_bucket_kernel(const int* __restrict__ dst,
                                                          int* __restrict__ bcnt,
                                                          int e, int n, int nbk) {
  __shared__ int h[1024];
  int T = e + n;
  int chunk = (T + gridDim.x - 1) / gridDim.x;
  int j0 = blockIdx.x * chunk;
  int j1 = min(j0 + chunk, T);
  for (int i = threadIdx.x; i < nbk; i += 256) h[i] = 0;
  __syncthreads();
  for (int j = j0 + threadIdx.x; j < j1; j += 256) {
    int d = (j < e) ? dst[j] : (j - e);
    atomicAdd(&h[d >> 7], 1);
  }
  __syncthreads();
  for (int i = threadIdx.x; i < nbk; i += 256)
    if (h[i]) atomicAdd(&bcnt[i], h[i]);
}

__global__ __launch_bounds__(1024) void scan_buckets_kernel(const int* __restrict__ bcnt,
                                                            int* __restrict__ bbase,
                                                            int nbk, int total) {
  __shared__ int lds[1024];
  int t = threadIdx.x;
  int v = (t < nbk) ? bcnt[t] : 0;
  int val = v;
  lds[t] = val; __syncthreads();
  for (int off = 1; off < 1024; off <<= 1) {
    int x = (t >= off) ? lds[t - off] : 0;
    __syncthreads();
    val += x;
    lds[t] = val;
    __syncthreads();
  }
  if (t < nbk) bbase[t] = val - v;
  if (t == 0) bbase[nbk] = total;
}

// scatter into bucket regions; 4B packed record = (src<<7) | (dst & 127)
__global__ __launch_bounds__(256) void scatter_bucket_kernel(const int* __restrict__ src,
                                                             const int* __restrict__ dst,
                                                             int* __restrict__ bfill,
                                                             unsigned* __restrict__ ebuf,
                                                             int e, int n, int nbk) {
  __shared__ int cntL[1024], baseL[1024];
  int T = e + n;
  int chunk = (T + gridDim.x - 1) / gridDim.x;
  int j0 = blockIdx.x * chunk;
  int j1 = min(j0 + chunk, T);
  for (int i = threadIdx.x; i < nbk; i += 256) cntL[i] = 0;
  __syncthreads();
  for (int j = j0 + threadIdx.x; j < j1; j += 256) {
    int d = (j < e) ? dst[j] : (j - e);
    atomicAdd(&cntL[d >> 7], 1);
  }
  __syncthreads();
  for (int i = threadIdx.x; i < nbk; i += 256) {
    int c = cntL[i];
    baseL[i] = c ? atomicAdd(&bfill[i], c) : 0;
    cntL[i] = 0;
  }
  __syncthreads();
  for (int j = j0 + threadIdx.x; j < j1; j += 256) {
    int s, d;
    if (j < e) { s = src[j]; d = dst[j]; } else { s = j - e; d = s; }
    int b = d >> 7;
    int r = atomicAdd(&cntL[b], 1);
    ebuf[baseL[b] + r] = ((unsigned)s << 7) | (unsigned)(d & 127);
  }
}

// pass C: in-LDS sort of each bucket by dst; emits rs, dis, sorted (src,dst)
__global__ __launch_bounds__(256) void sort_bucket_kernel(const int* __restrict__ bbase,
                                                          const unsigned* __restrict__ ebuf,
                                                          int2* __restrict__ ebuf2,
                                                          int* __restrict__ rs,
                                                          float* __restrict__ dis,
                                                          int n, int total) {
  __shared__ unsigned el[CAP];
  __shared__ int hist[BKT], excl[BKT], cur[BKT], scn[BKT];
  int b = blockIdx.x, t = threadIdx.x;
  int e0 = bbase[b], e1 = bbase[b + 1];
  int sz = e1 - e0;
  bool inl = (sz <= CAP);
  if (inl)
    for (int i = t; i < sz; i += 256) el[i] = ebuf[e0 + i];
  if (t < BKT) hist[t] = 0;
  __syncthreads();
  for (int i = t; i < sz; i += 256) {
    unsigned w = inl ? el[i] : ebuf[e0 + i];
    atomicAdd(&hist[w & (BKT - 1)], 1);
  }
  __syncthreads();
  int val = (t < BKT) ? hist[t] : 0;
  if (t < BKT) scn[t] = val;
  __syncthreads();
  for (int off = 1; off < BKT; off <<= 1) {
    int x = (t >= off && t < BKT) ? scn[t - off] : 0;
    __syncthreads();
    if (t < BKT) { val += x; scn[t] = val; }
    __syncthreads();
  }
  if (t < BKT) {
    int ex = val - hist[t];
    excl[t] = ex;
    cur[t] = 0;
    int d = (b << 7) + t;
    if (d < n) {
      rs[d] = e0 + ex;
      dis[d] = rsqrtf((float)hist[t]);  // deg >= 1 (self-loop)
    }
  }
  if (b == 0 && t == 0) rs[n] = total;
  __syncthreads();
  for (int i = t; i < sz; i += 256) {
    unsigned w = inl ? el[i] : ebuf[e0 + i];
    int dl = (int)(w & (BKT - 1));
    int pos = atomicAdd(&cur[dl], 1);
    ebuf2[e0 + excl[dl] + pos] = make_int2((int)(w >> 7), (b << 7) | dl);
  }
}

// pass D: (src,dst) -> (src, norm_bits | end_of_row_flag)  [written to esn]
__global__ void norm_kernel(const int2* __restrict__ ebuf2, const float* __restrict__ dis,
                            int2* __restrict__ esn, int T) {
  int j = blockIdx.x * blockDim.x + threadIdx.x;
  if (j >= T) return;
  int2 p = ebuf2[j];
  float nm = dis[p.x] * dis[p.y];
  unsigned bits = __float_as_uint(nm) & 0xfffffffeu;
  if (j + 1 == T || ebuf2[j + 1].y != p.y) bits |= 1u;
  esn[j] = make_int2(p.x, (int)bits);
}

// per-layer: fold dequant scale; compress to 4B = (src:17 | fac_bf14:14 | flag:1)
__global__ void fold_scale_kernel(const int2* __restrict__ esn,
                                  const float* __restrict__ hscale,
                                  unsigned* __restrict__ esnc, int T) {
  int j = blockIdx.x * blockDim.x + threadIdx.x;
  if (j >= T) return;
  int2 p = esn[j];
  unsigned bits = (unsigned)p.y;
  float nm = __uint_as_float(bits & 0xfffffffeu);
  float f = nm * hscale[p.x];
  unsigned fb = __float_as_uint(f) + 0x10000u;       // RNE on bit 17
  unsigned field = (fb >> 17) & 0x3fffu;             // exp8 + mant6
  esnc[j] = ((unsigned)p.x << 15) | (field << 1) | (bits & 1u);
}

__global__ void wave_bounds_kernel(const int* __restrict__ rs, int* __restrict__ A,
                                   int n, int nw, int eb) {
  int w = blockIdx.x * blockDim.x + threadIdx.x;
  if (w > nw) return;
  int target = w * eb;
  int lo = 0, hi = n;
  while (lo < hi) {
    int mid = (lo + hi) >> 1;
    if (rs[mid] < target) lo = mid + 1; else hi = mid;
  }
  A[w] = lo;
}

__global__ void softmax_w_kernel(const float* __restrict__ lw, float* __restrict__ w, int l) {
  if (threadIdx.x == 0 && blockIdx.x == 0) {
    float m = lw[0];
    for (int i = 1; i < l; ++i) m = fmaxf(m, lw[i]);
    float s = 0.f;
    for (int i = 0; i < l; ++i) s += expf(lw[i] - m);
    for (int i = 0; i < l; ++i) w[i] = expf(lw[i] - m) / s;
  }
}

__global__ void transpose_w_kernel(const float* __restrict__ W, unsigned short* __restrict__ Wt,
                                   int total) {
  int t = blockIdx.x * blockDim.x + threadIdx.x;
  if (t >= total) return;
  int l = t >> 14;
  int nc = (t >> 7) & 127;
  int kk = t & 127;
  Wt[t] = f2bf(W[(size_t)l * 16384 + kk * 128 + nc]);
}

// ---------------- embed: register-W, LDS-staged x, bf16 output ----------------

__global__ __launch_bounds__(256) void embed_kernel(const float* __restrict__ x,
                                                    const float* __restrict__ W,
                                                    const float* __restrict__ b,
                                                    unsigned short* __restrict__ xe16, int n) {
  __shared__ float xs[64][20];
  int tid = threadIdx.x;
  int c = tid & 127, half = tid >> 7;
  float wreg[16];
#pragma unroll
  for (int k = 0; k < 16; ++k) wreg[k] = W[k * 128 + c];
  float bc = b[c];
  int ntile = (n + 63) >> 6;
  for (int t = blockIdx.x; t < ntile; t += gridDim.x) {
    int row0 = t * 64;
    {
      int r = tid >> 2, q = tid & 3;
      int row = row0 + r;
      float4 v = (row < n) ? *(const float4*)(x + (size_t)row * 16 + q * 4)
                           : make_float4(0.f, 0.f, 0.f, 0.f);
      *(float4*)&xs[r][q * 4] = v;
    }
    __syncthreads();
    int rbase = half * 32;
    for (int rr = 0; rr < 32; ++rr) {
      int row = row0 + rbase + rr;
      if (row >= n) break;
      float acc = bc;
#pragma unroll
      for (int k = 0; k < 16; ++k) acc = fmaf(xs[rbase + rr][k], wreg[k], acc);
      xe16[(size_t)row * 128 + c] = f2bf(acc);
    }
    __syncthreads();
  }
}

// ---------------- fused (BN+ReLU+residual of prev layer) + MFMA GEMM ----------------

#define EPS 132   // padded LDS row stride (bf16 elems)

template<bool HASBN>
__global__ __launch_bounds__(256) void gemm_fused_kernel(
    const unsigned* __restrict__ aggbf,       // HASBN: packed bf16x2 agg (prev layer)
    const float* __restrict__ stats8,         // HASBN: 8 slices x 256 (prev layer)
    const float* __restrict__ gamma, const float* __restrict__ beta,
    const float* __restrict__ wsm, int layer, // prev layer idx
    unsigned* __restrict__ xe16,              // packed bf16x2 residual accumulator
    const unsigned short* __restrict__ Wt,
    unsigned char* __restrict__ Hq,           // int8 h table, 128 B/row
    float* __restrict__ hscale, int n) {      // per-row dequant scale
  __shared__ short8 wlds[2048];               // 32 KB
  __shared__ unsigned short ep[64 * EPS];     // 16.5 KB epilogue pack buffer
  __shared__ float sc_s[128], sh_s[128];
  int tid = threadIdx.x;
  const short* WtS = (const short*)Wt;
#pragma unroll
  for (int it = 0; it < 8; ++it) {
    int s = it * 256 + tid;
    int ln = s & 63, g = s >> 6;              // g = n0*4+ks
    int col = ((g >> 2) << 4) + (ln & 15);
    wlds[s] = *(const short8*)(WtS + (size_t)col * 128 + (g & 3) * 32 + (ln >> 4) * 8);
  }
  if (HASBN && tid < 128) {
    float s = 0.f, q = 0.f;
#pragma unroll
    for (int k = 0; k < 8; ++k) {
      s += stats8[k * 256 + tid];
      q += stats8[k * 256 + 128 + tid];
    }
    float invn = 1.f / (float)n;
    float mean = s * invn;
    float var = q * invn - mean * mean;
    float sc = gamma[tid] * rsqrtf(var + 1e-5f);
    sc_s[tid] = sc;
    sh_s[tid] = beta[tid] - mean * sc;
  }
  __syncthreads();

  int wid = tid >> 6, lane = tid & 63;
  int lrow = lane & 15, lk = lane >> 4;
  float wres = HASBN ? wsm[layer] : 0.f;

  int ntiles = (n + 63) >> 6;
  for (int tile = blockIdx.x; tile < ntiles; tile += gridDim.x) {
    int row = tile * 64 + wid * 16 + lrow;
    short8 afrag[4];
    if (row < n) {
      if (HASBN) {
        const unsigned* arow = aggbf + (size_t)row * 64;
        unsigned* xrow = xe16 + (size_t)row * 64;
#pragma unroll
        for (int ks = 0; ks < 4; ++ks) {
          int c0 = ks * 32 + lk * 8;          // first channel (8 channels = 4 words)
          uint4 av = *(const uint4*)(arow + (c0 >> 1));
          uint4 xw = *(const uint4*)(xrow + (c0 >> 1));
          unsigned aw[4] = {av.x, av.y, av.z, av.w};
          unsigned xv[4] = {xw.x, xw.y, xw.z, xw.w};
          unsigned xo[4];
          short8 af;
#pragma unroll
          for (int d = 0; d < 4; ++d) {
            int c = c0 + 2 * d;
            float v0 = fmaxf(fmaf(bf2f_lo(aw[d]), sc_s[c], sh_s[c]), 0.f);
            float v1 = fmaxf(fmaf(bf2f_hi(aw[d]), sc_s[c + 1], sh_s[c + 1]), 0.f);
            float xn0 = fmaf(wres, v0, bf2f_lo(xv[d]));
            float xn1 = fmaf(wres, v1, bf2f_hi(xv[d]));
            unsigned pw = pack_bf2(xn0, xn1);
            xo[d] = pw;
            af[2 * d]     = (short)(pw & 0xffff);
            af[2 * d + 1] = (short)(pw >> 16);
          }
          *(uint4*)(xrow + (c0 >> 1)) = make_uint4(xo[0], xo[1], xo[2], xo[3]);
          afrag[ks] = af;
        }
      } else {
        const short* AS = (const short*)xe16;
#pragma unroll
        for (int ks = 0; ks < 4; ++ks)
          afrag[ks] = *(const short8*)(AS + (size_t)row * 128 + ks * 32 + lk * 8);
      }
    } else {
#pragma unroll
      for (int ks = 0; ks < 4; ++ks) afrag[ks] = (short8)0;
    }
    f32x4 acc[8];
#pragma unroll
    for (int n0 = 0; n0 < 8; ++n0) acc[n0] = (f32x4)0.f;
#pragma unroll
    for (int ks = 0; ks < 4; ++ks)
#pragma unroll
      for (int n0 = 0; n0 < 8; ++n0)
        acc[n0] = __builtin_amdgcn_mfma_f32_16x16x32_bf16(
            afrag[ks], wlds[(n0 * 4 + ks) * 64 + lane], acc[n0], 0, 0, 0);

    // ---- epilogue: pack to LDS, per-row int8 quantization, coalesced store ----
    int eprow0 = wid * 16 + lk * 4;           // row within 64-row tile
#pragma unroll
    for (int n0 = 0; n0 < 8; ++n0) {
      int col = n0 * 16 + lrow;
#pragma unroll
      for (int r = 0; r < 4; ++r)
        ep[(eprow0 + r) * EPS + col] = f2bf(acc[n0][r]);
    }
    __syncthreads();
    int trow = tid >> 2;                      // 0..63
    int tchunk = tid & 3;                     // 32 channels per thread
    int orow = tile * 64 + trow;
    const unsigned short* srcl = ep + trow * EPS + tchunk * 32;
    float vals[32];
    float mx = 0.f;
#pragma unroll
    for (int c = 0; c < 4; ++c) {
      short8 ch = *(const short8*)(srcl + c * 8);
#pragma unroll
      for (int i = 0; i < 8; ++i) {
        float v = __uint_as_float(((unsigned)(unsigned short)ch[i]) << 16);
        vals[c * 8 + i] = v;
        mx = fmaxf(mx, __builtin_fabsf(v));
      }
    }
    mx = fmaxf(mx, __shfl_xor(mx, 1));        // 4 lanes of one row
    mx = fmaxf(mx, __shfl_xor(mx, 2));
    float inv = (mx > 0.f) ? 127.f / mx : 0.f;
    if (orow < n) {
      if (tchunk == 0) hscale[orow] = mx * (1.f / 127.f);
      unsigned q[8];
#pragma unroll
      for (int d = 0; d < 8; ++d) {
        unsigned b = 0;
#pragma unroll
        for (int j = 0; j < 4; ++j) {
          int qi = (int)rintf(vals[d * 4 + j] * inv);
          b |= ((unsigned)(qi & 0xff)) << (8 * j);
        }
        q[d] = b;
      }
      uint4* dst = (uint4*)(Hq + (size_t)orow * 128 + tchunk * 32);
      dst[0] = make_uint4(q[0], q[1], q[2], q[3]);
      dst[1] = make_uint4(q[4], q[5], q[6], q[7]);
    }
    __syncthreads();
  }
}

// ---------------- flag-stream segmented SpMM (int8, 4B compressed records) ----------------
// Record (wave-uniform): src:17 | fac_bf14:14 | flag:1. One rfl/edge; SALU decode.

#define SPMM_STEP(SW, VI)                                                  \
  {                                                                        \
    float fac = __uint_as_float(((SW) & 0x7ffeu) << 16);                   \
    a0 = fmaf(fac, (float)(signed char)((VI) & 0xff), a0);                 \
    a1 = fmaf(fac, (float)(signed char)((VI) >> 8), a1);                   \
    if ((SW) & 1u) {                                                       \
      aggbf[(size_t)row * 64 + lane] = pack_bf2(a0, a1);                   \
      t0 += a0; t1 += a1;                                                  \
      u0 = fmaf(a0, a0, u0); u1 = fmaf(a1, a1, u1);                        \
      a0 = 0.f; a1 = 0.f;                                                  \
      ++row;                                                               \
    }                                                                      \
  }

#define SPMM_GATHER(SW) (*(const unsigned short*)(hqb + (((SW) >> 8) & ~127u) + lane2))

__global__ __launch_bounds__(256) void spmm_kernel(
    const int* __restrict__ rs, const int* __restrict__ A,
    const unsigned* __restrict__ esnc, const unsigned char* __restrict__ hq,
    unsigned* __restrict__ aggbf, float* __restrict__ stats8, int n) {
  int tid = threadIdx.x;
  int wid = tid >> 6, lane = tid & 63;
  int lane2 = lane * 2;                      // byte offset within 128B row
  const char* hqb = (const char*)hq;
  int w = blockIdx.x * 4 + wid;
  int row = __builtin_amdgcn_readfirstlane(A[w]);
  int row_end = __builtin_amdgcn_readfirstlane(A[w + 1]);
  float t0 = 0.f, t1 = 0.f, u0 = 0.f, u1 = 0.f;
  if (row < row_end) {
    int e = __builtin_amdgcn_readfirstlane(rs[row]);
    int eend = __builtin_amdgcn_readfirstlane(rs[row_end]);
    float a0 = 0.f, a1 = 0.f;
    while ((e & 3) && e < eend) {              // peel to 16B alignment
      unsigned sw = rfl(esnc[e]);
      unsigned v = SPMM_GATHER(sw);
      SPMM_STEP(sw, v)
      ++e;
    }
    const uint4* e4 = (const uint4*)(esnc + e);
    int nq = (eend - e) >> 2;
    int i4 = 0;
    while (i4 + 2 <= nq) {                     // 8 edges per iter
      uint4 qa = e4[i4], qb = e4[i4 + 1];
      unsigned w0 = rfl(qa.x), w1 = rfl(qa.y), w2 = rfl(qa.z), w3 = rfl(qa.w);
      unsigned w4 = rfl(qb.x), w5 = rfl(qb.y), w6 = rfl(qb.z), w7 = rfl(qb.w);
      unsigned v0 = SPMM_GATHER(w0);
      unsigned v1 = SPMM_GATHER(w1);
      unsigned v2 = SPMM_GATHER(w2);
      unsigned v3 = SPMM_GATHER(w3);
      unsigned v4 = SPMM_GATHER(w4);
      unsigned v5 = SPMM_GATHER(w5);
      unsigned v6 = SPMM_GATHER(w6);
      unsigned v7 = SPMM_GATHER(w7);
      SPMM_STEP(w0, v0) SPMM_STEP(w1, v1)
      SPMM_STEP(w2, v2) SPMM_STEP(w3, v3)
      SPMM_STEP(w4, v4) SPMM_STEP(w5, v5)
      SPMM_STEP(w6, v6) SPMM_STEP(w7, v7)
      i4 += 2;
    }
    e += i4 << 2;
    while (e < eend) {
      unsigned sw = rfl(esnc[e]);
      unsigned v = SPMM_GATHER(sw);
      SPMM_STEP(sw, v)
      ++e;
    }
  }
  __shared__ float red[4][256];
  red[0][tid] = t0; red[1][tid] = t1; red[2][tid] = u0; red[3][tid] = u1;
  __syncthreads();
  float v = red[wid][lane] + red[wid][64 + lane] + red[wid][128 + lane] + red[wid][192 + lane];
  int c = (wid == 0) ? (2 * lane) : (wid == 1) ? (2 * lane + 1)
        : (wid == 2) ? (128 + 2 * lane) : (129 + 2 * lane);
  atomicAdd(&stats8[(blockIdx.x & 7) * 256 + c], v);
}

// ---------------- final FC (fused BN of last layer; bf16 xe) ----------------

__global__ __launch_bounds__(256) void fc_node_kernel(
    const unsigned* __restrict__ aggbf, const float* __restrict__ stats8,
    const float* __restrict__ gamma, const float* __restrict__ beta,
    const float* __restrict__ wsm, int layer,
    const unsigned* __restrict__ xe16, const float* __restrict__ fcW,
    float* __restrict__ y, int n) {
  __shared__ float sc_s[128], sh_s[128];
  int tid = threadIdx.x;
  if (tid < 128) {
    float s = 0.f, q = 0.f;
#pragma unroll
    for (int k = 0; k < 8; ++k) {
      s += stats8[k * 256 + tid];
      q += stats8[k * 256 + 128 + tid];
    }
    float invn = 1.f / (float)n;
    float mean = s * invn;
    float var = q * invn - mean * mean;
    float sc = gamma[tid] * rsqrtf(var + 1e-5f);
    sc_s[tid] = sc;
    sh_s[tid] = beta[tid] - mean * sc;
  }
  __syncthreads();
  int wid = tid >> 6, lane = tid & 63;
  int r = blockIdx.x * 4 + wid;
  if (r >= n) return;
  float w = wsm[layer];
  unsigned av = aggbf[(size_t)r * 64 + lane];
  unsigned xv = xe16[(size_t)r * 64 + lane];
  int c0 = lane * 2, c1 = c0 + 1;
  float x0 = fmaf(w, fmaxf(fmaf(bf2f_lo(av), sc_s[c0], sh_s[c0]), 0.f), bf2f_lo(xv));
  float x1 = fmaf(w, fmaxf(fmaf(bf2f_hi(av), sc_s[c1], sh_s[c1]), 0.f), bf2f_hi(xv));
  float a00 = x0 * fcW[c0 * 2 + 0] + x1 * fcW[c1 * 2 + 0];
  float a01 = x0 * fcW[c0 * 2 + 1] + x1 * fcW[c1 * 2 + 1];
  float a10 = x0 * fcW[(128 + c0) * 2 + 0] + x1 * fcW[(128 + c1) * 2 + 0];
  float a11 = x0 * fcW[(128 + c0) * 2 + 1] + x1 * fcW[(128 + c1) * 2 + 1];
#pragma unroll
  for (int off = 32; off; off >>= 1) {
    a00 += __shfl_down(a00, off);
    a01 += __shfl_down(a01, off);
    a10 += __shfl_down(a10, off);
    a11 += __shfl_down(a11, off);
  }
  if (lane == 0) *(float4*)(y + (size_t)r * 4) = make_float4(a00, a01, a10, a11);
}

__global__ void edge_out_kernel(const float* __restrict__ y, const int* __restrict__ eo,
                                const float* __restrict__ fcb, float* __restrict__ out, int m) {
  int j = blockIdx.x * blockDim.x + threadIdx.x;
  if (j >= m) return;
  int a = eo[j], b = eo[m + j];
  float4 ya = *(const float4*)(y + (size_t)a * 4);
  float4 yb = *(const float4*)(y + (size_t)b * 4);
  out[(size_t)j * 2 + 0] = ya.x + yb.z + fcb[0];
  out[(size_t)j * 2 + 1] = ya.y + yb.w + fcb[1];
}

// ---------------------------------------------------------------------------

extern "C" void kernel_launch(void* const* d_in, const int* in_sizes, int n_in,
                              void* d_out, int out_size, void* d_ws, size_t ws_size,
                              hipStream_t stream) {
  const float* x     = (const float*)d_in[0];
  const int*   ei    = (const int*)d_in[1];
  const int*   eo    = (const int*)d_in[2];
  const float* embW  = (const float*)d_in[3];
  const float* embB  = (const float*)d_in[4];
  const float* convW = (const float*)d_in[5];
  const float* gamma = (const float*)d_in[7];
  const float* beta  = (const float*)d_in[8];
  const float* lw    = (const float*)d_in[9];
  const float* fcW   = (const float*)d_in[10];
  const float* fcb   = (const float*)d_in[11];
  float* out = (float*)d_out;

  const int n = in_sizes[0] / 16;          // 100000
  const int e = in_sizes[1] / 2;           // 1600000
  const int m = in_sizes[2] / 2;           // 400000
  const int L = in_sizes[5] / (128 * 128); // 6

  const int T   = e + n;                   // total edges incl self loops
  const int EB  = (T + NW - 1) / NW;       // edges per wave target
  const int nbk = (n + BKT - 1) / BKT;     // 782 buckets

  const int* esrc = ei;
  const int* edst = ei + e;

  char* wsp = (char*)d_ws;
  size_t off = 0;
  auto take = [&](size_t bytes) -> void* {
    void* p = wsp + off;
    off = (off + bytes + 255) & ~(size_t)255;
    return p;
  };
  int*            bcnt     = (int*)take((size_t)(nbk + 1) * 4);
  int*            bbase    = (int*)take((size_t)(nbk + 1) * 4);
  int*            bfill    = (int*)take((size_t)(nbk + 1) * 4);
  int*            rs       = (int*)take((size_t)(n + 1) * 4);
  float*          dis      = (float*)take((size_t)n * 4);
  float*          hscale   = (float*)take((size_t)n * 4);
  float*          wsm      = (float*)take(64 * 4);
  float*          stats    = (float*)take((size_t)L * 8 * 256 * 4);
  int*            A        = (int*)take((size_t)(NW + 1) * 4);
  unsigned*       ebuf     = (unsigned*)take((size_t)T * 4);  // packed bucketed records
  int2*           ebuf2    = (int2*)take((size_t)T * 8);      // sorted (src,dst)
  int2*           esn      = (int2*)take((size_t)T * 8);      // static (src, norm|flag)
  unsigned*       esnc     = (unsigned*)take((size_t)T * 4);  // per-layer folded records
  unsigned short* xe16     = (unsigned short*)take((size_t)n * 128 * 2);
  unsigned char*  hq       = (unsigned char*)take((size_t)n * 128);
  unsigned*       aggbf    = (unsigned*)take((size_t)n * 64 * 4);
  unsigned short* Wt       = (unsigned short*)take((size_t)L * 128 * 128 * 2);
  float*          y        = (float*)take((size_t)n * 4 * 4);
  if (off > ws_size || nbk > 1024) return;

  // --- preprocessing: radix sort by dst ---
  hipMemsetAsync(bcnt, 0, (size_t)(nbk + 1) * 4, stream);
  hipMemsetAsync(stats, 0, (size_t)L * 8 * 256 * 4, stream);
  hist_bucket_kernel<<<512, 256, 0, stream>>>(edst, bcnt, e, n, nbk);
  scan_buckets_kernel<<<1, 1024, 0, stream>>>(bcnt, bbase, nbk, T);
  hipMemcpyAsync(bfill, bbase, (size_t)nbk * 4, hipMemcpyDeviceToDevice, stream);
  scatter_bucket_kernel<<<512, 256, 0, stream>>>(esrc, edst, bfill, ebuf, e, n, nbk);
  sort_bucket_kernel<<<nbk, 256, 0, stream>>>(bbase, ebuf, ebuf2, rs, dis, n, T);
  norm_kernel<<<(T + 255) / 256, 256, 0, stream>>>(ebuf2, dis, esn, T);
  wave_bounds_kernel<<<(NW + 256) / 256, 256, 0, stream>>>(rs, A, n, NW, EB);
  softmax_w_kernel<<<1, 64, 0, stream>>>(lw, wsm, L);
  transpose_w_kernel<<<(L * 16384 + 255) / 256, 256, 0, stream>>>(convW, Wt, L * 16384);

  // --- embed (bf16 xe) ---
  embed_kernel<<<1024, 256, 0, stream>>>(x, embW, embB, xe16, n);

  // --- 6 GCN layers (conv_b dropped: cancels under BN) ---
  const int ntiles = (n + 63) >> 6;
  const int gemm_grid = (ntiles + 1) / 2;   // exactly <=2 tiles per block
  for (int i = 0; i < L; ++i) {
    if (i == 0) {
      gemm_fused_kernel<false><<<gemm_grid, 256, 0, stream>>>(
          nullptr, nullptr, nullptr, nullptr, wsm, 0, (unsigned*)xe16,
          Wt, hq, hscale, n);
    } else {
      gemm_fused_kernel<true><<<gemm_grid, 256, 0, stream>>>(
          aggbf, stats + (size_t)(i - 1) * 2048,
          gamma + (size_t)(i - 1) * 128, beta + (size_t)(i - 1) * 128, wsm, i - 1,
          (unsigned*)xe16, Wt + (size_t)i * 16384, hq, hscale, n);
    }
    fold_scale_kernel<<<(T + 255) / 256, 256, 0, stream>>>(esn, hscale, esnc, T);
    spmm_kernel<<<NW / 4, 256, 0, stream>>>(rs, A, esnc, hq,
                                            aggbf, stats + (size_t)i * 2048, n);
  }

  // --- final FC (fused BN of layer L-1) ---
  fc_node_kernel<<<(n + 3) / 4, 256, 0, stream>>>(
      aggbf, stats + (size_t)(L - 1) * 2048,
      gamma + (size_t)(L - 1) * 128, beta + (size_t)(L - 1) * 128, wsm, L - 1,
      (const unsigned*)xe16, fcW, y, n);
  edge_out_kernel<<<(m + 255) / 256, 256, 0, stream>>>(y, eo, fcb, out, m);
}

// Round 18
// 559.961 us; speedup vs baseline: 1.2569x; 1.0541x over previous
//
#include <hip/hip_runtime.h>

// ---------------------------------------------------------------------------
// MultiEdgeClassifier: 6-layer GCN + BN + weighted residual + edge-pair FC
// N=100k nodes, HID=128, E=1.6M edges (+N self loops), E_OUT=400k
// Round 17: fold pass fused into SpMM as a chunked per-wave LDS pre-phase
//           (parallel per-lane hscale gathers, 4B records staged in LDS);
//           tiny kernels (wave_bounds/transpose/softmax) merged into one.
// ---------------------------------------------------------------------------

#define NW 8192      // waves for spmm (2048 blocks x 4)
#define BKT 128      // dsts per bucket
#define CAP 6144     // max edges per bucket staged in LDS (mean ~2175)
#define CHUNK 512    // edges folded into LDS per wave per pass

typedef __attribute__((ext_vector_type(8))) short short8;
typedef __attribute__((ext_vector_type(4))) float f32x4;

static __device__ __forceinline__ unsigned short f2bf(float f) {
  unsigned u = __float_as_uint(f);
  u = u + 0x7fffu + ((u >> 16) & 1u);   // RNE
  return (unsigned short)(u >> 16);
}
static __device__ __forceinline__ float bf2f_lo(unsigned v) {
  return __uint_as_float(v << 16);
}
static __device__ __forceinline__ float bf2f_hi(unsigned v) {
  return __uint_as_float(v & 0xffff0000u);
}
static __device__ __forceinline__ unsigned pack_bf2(float a, float b) {
  return (unsigned)f2bf(a) | ((unsigned)f2bf(b) << 16);
}
static __device__ __forceinline__ unsigned rfl(unsigned v) {
  return (unsigned)__builtin_amdgcn_readfirstlane((int)v);
}

// ---------------- preprocessing: two-level radix sort by dst ----------------

__global__ __launch_bounds__(256) void hist_bucket_kernel(const int* __restrict__ dst,
                                                          int* __restrict__ bcnt,
                                                          int e, int n, int nbk) {
  __shared__ int h[1024];
  int T = e + n;
  int chunk = (T + gridDim.x - 1) / gridDim.x;
  int j0 = blockIdx.x * chunk;
  int j1 = min(j0 + chunk, T);
  for (int i = threadIdx.x; i < nbk; i += 256) h[i] = 0;
  __syncthreads();
  for (int j = j0 + threadIdx.x; j < j1; j += 256) {
    int d = (j < e) ? dst[j] : (j - e);
    atomicAdd(&h[d >> 7], 1);
  }
  __syncthreads();
  for (int i = threadIdx.x; i < nbk; i += 256)
    if (h[i]) atomicAdd(&bcnt[i], h[i]);
}

__global__ __launch_bounds__(1024) void scan_buckets_kernel(const int* __restrict__ bcnt,
                                                            int* __restrict__ bbase,
                                                            int nbk, int total) {
  __shared__ int lds[1024];
  int t = threadIdx.x;
  int v = (t < nbk) ? bcnt[t] : 0;
  int val = v;
  lds[t] = val; __syncthreads();
  for (int off = 1; off < 1024; off <<= 1) {
    int x = (t >= off) ? lds[t - off] : 0;
    __syncthreads();
    val += x;
    lds[t] = val;
    __syncthreads();
  }
  if (t < nbk) bbase[t] = val - v;
  if (t == 0) bbase[nbk] = total;
}

// scatter into bucket regions; 4B packed record = (src<<7) | (dst & 127)
__global__ __launch_bounds__(256) void scatter_bucket_kernel(const int* __restrict__ src,
                                                             const int* __restrict__ dst,
                                                             int* __restrict__ bfill,
                                                             unsigned* __restrict__ ebuf,
                                                             int e, int n, int nbk) {
  __shared__ int cntL[1024], baseL[1024];
  int T = e + n;
  int chunk = (T + gridDim.x - 1) / gridDim.x;
  int j0 = blockIdx.x * chunk;
  int j1 = min(j0 + chunk, T);
  for (int i = threadIdx.x; i < nbk; i += 256) cntL[i] = 0;
  __syncthreads();
  for (int j = j0 + threadIdx.x; j < j1; j += 256) {
    int d = (j < e) ? dst[j] : (j - e);
    atomicAdd(&cntL[d >> 7], 1);
  }
  __syncthreads();
  for (int i = threadIdx.x; i < nbk; i += 256) {
    int c = cntL[i];
    baseL[i] = c ? atomicAdd(&bfill[i], c) : 0;
    cntL[i] = 0;
  }
  __syncthreads();
  for (int j = j0 + threadIdx.x; j < j1; j += 256) {
    int s, d;
    if (j < e) { s = src[j]; d = dst[j]; } else { s = j - e; d = s; }
    int b = d >> 7;
    int r = atomicAdd(&cntL[b], 1);
    ebuf[baseL[b] + r] = ((unsigned)s << 7) | (unsigned)(d & 127);
  }
}

// pass C: in-LDS sort of each bucket by dst; emits rs, dis, sorted (src,dst)
__global__ __launch_bounds__(256) void sort_bucket_kernel(const int* __restrict__ bbase,
                                                          const unsigned* __restrict__ ebuf,
                                                          int2* __restrict__ ebuf2,
                                                          int* __restrict__ rs,
                                                          float* __restrict__ dis,
                                                          int n, int total) {
  __shared__ unsigned el[CAP];
  __shared__ int hist[BKT], excl[BKT], cur[BKT], scn[BKT];
  int b = blockIdx.x, t = threadIdx.x;
  int e0 = bbase[b], e1 = bbase[b + 1];
  int sz = e1 - e0;
  bool inl = (sz <= CAP);
  if (inl)
    for (int i = t; i < sz; i += 256) el[i] = ebuf[e0 + i];
  if (t < BKT) hist[t] = 0;
  __syncthreads();
  for (int i = t; i < sz; i += 256) {
    unsigned w = inl ? el[i] : ebuf[e0 + i];
    atomicAdd(&hist[w & (BKT - 1)], 1);
  }
  __syncthreads();
  int val = (t < BKT) ? hist[t] : 0;
  if (t < BKT) scn[t] = val;
  __syncthreads();
  for (int off = 1; off < BKT; off <<= 1) {
    int x = (t >= off && t < BKT) ? scn[t - off] : 0;
    __syncthreads();
    if (t < BKT) { val += x; scn[t] = val; }
    __syncthreads();
  }
  if (t < BKT) {
    int ex = val - hist[t];
    excl[t] = ex;
    cur[t] = 0;
    int d = (b << 7) + t;
    if (d < n) {
      rs[d] = e0 + ex;
      dis[d] = rsqrtf((float)hist[t]);  // deg >= 1 (self-loop)
    }
  }
  if (b == 0 && t == 0) rs[n] = total;
  __syncthreads();
  for (int i = t; i < sz; i += 256) {
    unsigned w = inl ? el[i] : ebuf[e0 + i];
    int dl = (int)(w & (BKT - 1));
    int pos = atomicAdd(&cur[dl], 1);
    ebuf2[e0 + excl[dl] + pos] = make_int2((int)(w >> 7), (b << 7) | dl);
  }
}

// pass D: (src,dst) -> (src, norm_bits | end_of_row_flag)  [written to esn]
__global__ void norm_kernel(const int2* __restrict__ ebuf2, const float* __restrict__ dis,
                            int2* __restrict__ esn, int T) {
  int j = blockIdx.x * blockDim.x + threadIdx.x;
  if (j >= T) return;
  int2 p = ebuf2[j];
  float nm = dis[p.x] * dis[p.y];
  unsigned bits = __float_as_uint(nm) & 0xfffffffeu;
  if (j + 1 == T || ebuf2[j + 1].y != p.y) bits |= 1u;
  esn[j] = make_int2(p.x, (int)bits);
}

// merged small kernels: wave bounds | W transpose | softmax(layer weights)
__global__ void misc_kernel(const int* __restrict__ rs, int* __restrict__ A,
                            int n, int nw, int eb, int wbBlocks,
                            const float* __restrict__ W, unsigned short* __restrict__ Wt,
                            int wtotal, int wtBlocks,
                            const float* __restrict__ lw, float* __restrict__ wsm, int l) {
  int b = blockIdx.x;
  if (b < wbBlocks) {
    int w = b * 256 + threadIdx.x;
    if (w > nw) return;
    int target = w * eb;
    int lo = 0, hi = n;
    while (lo < hi) {
      int mid = (lo + hi) >> 1;
      if (rs[mid] < target) lo = mid + 1; else hi = mid;
    }
    A[w] = lo;
  } else if (b < wbBlocks + wtBlocks) {
    int t = (b - wbBlocks) * 256 + threadIdx.x;
    if (t >= wtotal) return;
    int ll = t >> 14;
    int nc = (t >> 7) & 127;
    int kk = t & 127;
    Wt[t] = f2bf(W[(size_t)ll * 16384 + kk * 128 + nc]);
  } else if (threadIdx.x == 0) {
    float m = lw[0];
    for (int i = 1; i < l; ++i) m = fmaxf(m, lw[i]);
    float s = 0.f;
    for (int i = 0; i < l; ++i) s += expf(lw[i] - m);
    for (int i = 0; i < l; ++i) wsm[i] = expf(lw[i] - m) / s;
  }
}

// ---------------- embed: register-W, LDS-staged x, bf16 output ----------------

__global__ __launch_bounds__(256) void embed_kernel(const float* __restrict__ x,
                                                    const float* __restrict__ W,
                                                    const float* __restrict__ b,
                                                    unsigned short* __restrict__ xe16, int n) {
  __shared__ float xs[64][20];
  int tid = threadIdx.x;
  int c = tid & 127, half = tid >> 7;
  float wreg[16];
#pragma unroll
  for (int k = 0; k < 16; ++k) wreg[k] = W[k * 128 + c];
  float bc = b[c];
  int ntile = (n + 63) >> 6;
  for (int t = blockIdx.x; t < ntile; t += gridDim.x) {
    int row0 = t * 64;
    {
      int r = tid >> 2, q = tid & 3;
      int row = row0 + r;
      float4 v = (row < n) ? *(const float4*)(x + (size_t)row * 16 + q * 4)
                           : make_float4(0.f, 0.f, 0.f, 0.f);
      *(float4*)&xs[r][q * 4] = v;
    }
    __syncthreads();
    int rbase = half * 32;
    for (int rr = 0; rr < 32; ++rr) {
      int row = row0 + rbase + rr;
      if (row >= n) break;
      float acc = bc;
#pragma unroll
      for (int k = 0; k < 16; ++k) acc = fmaf(xs[rbase + rr][k], wreg[k], acc);
      xe16[(size_t)row * 128 + c] = f2bf(acc);
    }
    __syncthreads();
  }
}

// ---------------- fused (BN+ReLU+residual of prev layer) + MFMA GEMM ----------------

#define EPS 132   // padded LDS row stride (bf16 elems)

template<bool HASBN>
__global__ __launch_bounds__(256) void gemm_fused_kernel(
    const unsigned* __restrict__ aggbf,       // HASBN: packed bf16x2 agg (prev layer)
    const float* __restrict__ stats8,         // HASBN: 8 slices x 256 (prev layer)
    const float* __restrict__ gamma, const float* __restrict__ beta,
    const float* __restrict__ wsm, int layer, // prev layer idx
    unsigned* __restrict__ xe16,              // packed bf16x2 residual accumulator
    const unsigned short* __restrict__ Wt,
    unsigned char* __restrict__ Hq,           // int8 h table, 128 B/row
    float* __restrict__ hscale, int n) {      // per-row dequant scale
  __shared__ short8 wlds[2048];               // 32 KB
  __shared__ unsigned short ep[64 * EPS];     // 16.5 KB epilogue pack buffer
  __shared__ float sc_s[128], sh_s[128];
  int tid = threadIdx.x;
  const short* WtS = (const short*)Wt;
#pragma unroll
  for (int it = 0; it < 8; ++it) {
    int s = it * 256 + tid;
    int ln = s & 63, g = s >> 6;              // g = n0*4+ks
    int col = ((g >> 2) << 4) + (ln & 15);
    wlds[s] = *(const short8*)(WtS + (size_t)col * 128 + (g & 3) * 32 + (ln >> 4) * 8);
  }
  if (HASBN && tid < 128) {
    float s = 0.f, q = 0.f;
#pragma unroll
    for (int k = 0; k < 8; ++k) {
      s += stats8[k * 256 + tid];
      q += stats8[k * 256 + 128 + tid];
    }
    float invn = 1.f / (float)n;
    float mean = s * invn;
    float var = q * invn - mean * mean;
    float sc = gamma[tid] * rsqrtf(var + 1e-5f);
    sc_s[tid] = sc;
    sh_s[tid] = beta[tid] - mean * sc;
  }
  __syncthreads();

  int wid = tid >> 6, lane = tid & 63;
  int lrow = lane & 15, lk = lane >> 4;
  float wres = HASBN ? wsm[layer] : 0.f;

  int ntiles = (n + 63) >> 6;
  for (int tile = blockIdx.x; tile < ntiles; tile += gridDim.x) {
    int row = tile * 64 + wid * 16 + lrow;
    short8 afrag[4];
    if (row < n) {
      if (HASBN) {
        const unsigned* arow = aggbf + (size_t)row * 64;
        unsigned* xrow = xe16 + (size_t)row * 64;
#pragma unroll
        for (int ks = 0; ks < 4; ++ks) {
          int c0 = ks * 32 + lk * 8;          // first channel (8 channels = 4 words)
          uint4 av = *(const uint4*)(arow + (c0 >> 1));
          uint4 xw = *(const uint4*)(xrow + (c0 >> 1));
          unsigned aw[4] = {av.x, av.y, av.z, av.w};
          unsigned xv[4] = {xw.x, xw.y, xw.z, xw.w};
          unsigned xo[4];
          short8 af;
#pragma unroll
          for (int d = 0; d < 4; ++d) {
            int c = c0 + 2 * d;
            float v0 = fmaxf(fmaf(bf2f_lo(aw[d]), sc_s[c], sh_s[c]), 0.f);
            float v1 = fmaxf(fmaf(bf2f_hi(aw[d]), sc_s[c + 1], sh_s[c + 1]), 0.f);
            float xn0 = fmaf(wres, v0, bf2f_lo(xv[d]));
            float xn1 = fmaf(wres, v1, bf2f_hi(xv[d]));
            unsigned pw = pack_bf2(xn0, xn1);
            xo[d] = pw;
            af[2 * d]     = (short)(pw & 0xffff);
            af[2 * d + 1] = (short)(pw >> 16);
          }
          *(uint4*)(xrow + (c0 >> 1)) = make_uint4(xo[0], xo[1], xo[2], xo[3]);
          afrag[ks] = af;
        }
      } else {
        const short* AS = (const short*)xe16;
#pragma unroll
        for (int ks = 0; ks < 4; ++ks)
          afrag[ks] = *(const short8*)(AS + (size_t)row * 128 + ks * 32 + lk * 8);
      }
    } else {
#pragma unroll
      for (int ks = 0; ks < 4; ++ks) afrag[ks] = (short8)0;
    }
    f32x4 acc[8];
#pragma unroll
    for (int n0 = 0; n0 < 8; ++n0) acc[n0] = (f32x4)0.f;
#pragma unroll
    for (int ks = 0; ks < 4; ++ks)
#pragma unroll
      for (int n0 = 0; n0 < 8; ++n0)
        acc[n0] = __builtin_amdgcn_mfma_f32_16x16x32_bf16(
            afrag[ks], wlds[(n0 * 4 + ks) * 64 + lane], acc[n0], 0, 0, 0);

    // ---- epilogue: pack to LDS, per-row int8 quantization, coalesced store ----
    int eprow0 = wid * 16 + lk * 4;           // row within 64-row tile
#pragma unroll
    for (int n0 = 0; n0 < 8; ++n0) {
      int col = n0 * 16 + lrow;
#pragma unroll
      for (int r = 0; r < 4; ++r)
        ep[(eprow0 + r) * EPS + col] = f2bf(acc[n0][r]);
    }
    __syncthreads();
    int trow = tid >> 2;                      // 0..63
    int tchunk = tid & 3;                     // 32 channels per thread
    int orow = tile * 64 + trow;
    const unsigned short* srcl = ep + trow * EPS + tchunk * 32;
    float vals[32];
    float mx = 0.f;
#pragma unroll
    for (int c = 0; c < 4; ++c) {
      short8 ch = *(const short8*)(srcl + c * 8);
#pragma unroll
      for (int i = 0; i < 8; ++i) {
        float v = __uint_as_float(((unsigned)(unsigned short)ch[i]) << 16);
        vals[c * 8 + i] = v;
        mx = fmaxf(mx, __builtin_fabsf(v));
      }
    }
    mx = fmaxf(mx, __shfl_xor(mx, 1));        // 4 lanes of one row
    mx = fmaxf(mx, __shfl_xor(mx, 2));
    float inv = (mx > 0.f) ? 127.f / mx : 0.f;
    if (orow < n) {
      if (tchunk == 0) hscale[orow] = mx * (1.f / 127.f);
      unsigned q[8];
#pragma unroll
      for (int d = 0; d < 8; ++d) {
        unsigned b = 0;
#pragma unroll
        for (int j = 0; j < 4; ++j) {
          int qi = (int)rintf(vals[d * 4 + j] * inv);
          b |= ((unsigned)(qi & 0xff)) << (8 * j);
        }
        q[d] = b;
      }
      uint4* dst = (uint4*)(Hq + (size_t)orow * 128 + tchunk * 32);
      dst[0] = make_uint4(q[0], q[1], q[2], q[3]);
      dst[1] = make_uint4(q[4], q[5], q[6], q[7]);
    }
    __syncthreads();
  }
}

// ---------------- flag-stream segmented SpMM with fused per-chunk fold ----------------
// Per wave: chunk edges into LDS as 4B records (src:17|fac_bf14:14|flag:1);
// fold phase gathers hscale[src] per-lane in parallel. Inner loop = R14 shape.

#define SPMM_STEP(SW, VI)                                                  \
  {                                                                        \
    float fac = __uint_as_float(((SW) & 0x7ffeu) << 16);                   \
    a0 = fmaf(fac, (float)(signed char)((VI) & 0xff), a0);                 \
    a1 = fmaf(fac, (float)(signed char)((VI) >> 8), a1);                   \
    if ((SW) & 1u) {                                                       \
      aggbf[(size_t)row * 64 + lane] = pack_bf2(a0, a1);                   \
      t0 += a0; t1 += a1;                                                  \
      u0 = fmaf(a0, a0, u0); u1 = fmaf(a1, a1, u1);                        \
      a0 = 0.f; a1 = 0.f;                                                  \
      ++row;                                                               \
    }                                                                      \
  }

#define SPMM_GATHER(SW) (*(const unsigned short*)(hqb + (((SW) >> 8) & ~127u) + lane2))

__global__ __launch_bounds__(256) void spmm_kernel(
    const int* __restrict__ rs, const int* __restrict__ A,
    const int2* __restrict__ esn, const float* __restrict__ hscale,
    const unsigned char* __restrict__ hq,
    unsigned* __restrict__ aggbf, float* __restrict__ stats8, int n) {
  __shared__ unsigned lrec[4][CHUNK];        // 8 KB fold staging
  int tid = threadIdx.x;
  int wid = tid >> 6, lane = tid & 63;
  int lane2 = lane * 2;                      // byte offset within 128B row
  const char* hqb = (const char*)hq;
  unsigned* lr = lrec[wid];
  int w = blockIdx.x * 4 + wid;
  int row = __builtin_amdgcn_readfirstlane(A[w]);
  int row_end = __builtin_amdgcn_readfirstlane(A[w + 1]);
  float t0 = 0.f, t1 = 0.f, u0 = 0.f, u1 = 0.f;
  if (row < row_end) {
    int e0 = __builtin_amdgcn_readfirstlane(rs[row]);
    int eend = __builtin_amdgcn_readfirstlane(rs[row_end]);
    float a0 = 0.f, a1 = 0.f;
    for (int base = e0; base < eend; base += CHUNK) {
      int cnt = min(CHUNK, eend - base);
      // fold phase: lanes cooperatively compress records into LDS
      for (int i = lane; i < cnt; i += 64) {
        int2 p = esn[base + i];
        unsigned bits = (unsigned)p.y;
        float f = __uint_as_float(bits & 0xfffffffeu) * hscale[p.x];
        unsigned fb = __float_as_uint(f) + 0x10000u;     // RNE on bit 17
        lr[i] = ((unsigned)p.x << 15) | (((fb >> 17) & 0x3fffu) << 1) | (bits & 1u);
      }
      __asm__ volatile("s_waitcnt lgkmcnt(0)" ::: "memory");
      int i = 0;
      for (; i + 8 <= cnt; i += 8) {
        uint4 qa = *(const uint4*)(lr + i);
        uint4 qb = *(const uint4*)(lr + i + 4);
        unsigned w0 = rfl(qa.x), w1 = rfl(qa.y), w2 = rfl(qa.z), w3 = rfl(qa.w);
        unsigned w4 = rfl(qb.x), w5 = rfl(qb.y), w6 = rfl(qb.z), w7 = rfl(qb.w);
        unsigned v0 = SPMM_GATHER(w0);
        unsigned v1 = SPMM_GATHER(w1);
        unsigned v2 = SPMM_GATHER(w2);
        unsigned v3 = SPMM_GATHER(w3);
        unsigned v4 = SPMM_GATHER(w4);
        unsigned v5 = SPMM_GATHER(w5);
        unsigned v6 = SPMM_GATHER(w6);
        unsigned v7 = SPMM_GATHER(w7);
        SPMM_STEP(w0, v0) SPMM_STEP(w1, v1)
        SPMM_STEP(w2, v2) SPMM_STEP(w3, v3)
        SPMM_STEP(w4, v4) SPMM_STEP(w5, v5)
        SPMM_STEP(w6, v6) SPMM_STEP(w7, v7)
      }
      for (; i < cnt; ++i) {
        unsigned sw = rfl(lr[i]);
        unsigned v = SPMM_GATHER(sw);
        SPMM_STEP(sw, v)
      }
      __asm__ volatile("" ::: "memory");     // keep LDS reuse ordered across chunks
    }
  }
  __shared__ float red[4][256];
  red[0][tid] = t0; red[1][tid] = t1; red[2][tid] = u0; red[3][tid] = u1;
  __syncthreads();
  float v = red[wid][lane] + red[wid][64 + lane] + red[wid][128 + lane] + red[wid][192 + lane];
  int c = (wid == 0) ? (2 * lane) : (wid == 1) ? (2 * lane + 1)
        : (wid == 2) ? (128 + 2 * lane) : (129 + 2 * lane);
  atomicAdd(&stats8[(blockIdx.x & 7) * 256 + c], v);
}

// ---------------- final FC (fused BN of last layer; bf16 xe) ----------------

__global__ __launch_bounds__(256) void fc_node_kernel(
    const unsigned* __restrict__ aggbf, const float* __restrict__ stats8,
    const float* __restrict__ gamma, const float* __restrict__ beta,
    const float* __restrict__ wsm, int layer,
    const unsigned* __restrict__ xe16, const float* __restrict__ fcW,
    float* __restrict__ y, int n) {
  __shared__ float sc_s[128], sh_s[128];
  int tid = threadIdx.x;
  if (tid < 128) {
    float s = 0.f, q = 0.f;
#pragma unroll
    for (int k = 0; k < 8; ++k) {
      s += stats8[k * 256 + tid];
      q += stats8[k * 256 + 128 + tid];
    }
    float invn = 1.f / (float)n;
    float mean = s * invn;
    float var = q * invn - mean * mean;
    float sc = gamma[tid] * rsqrtf(var + 1e-5f);
    sc_s[tid] = sc;
    sh_s[tid] = beta[tid] - mean * sc;
  }
  __syncthreads();
  int wid = tid >> 6, lane = tid & 63;
  int r = blockIdx.x * 4 + wid;
  if (r >= n) return;
  float w = wsm[layer];
  unsigned av = aggbf[(size_t)r * 64 + lane];
  unsigned xv = xe16[(size_t)r * 64 + lane];
  int c0 = lane * 2, c1 = c0 + 1;
  float x0 = fmaf(w, fmaxf(fmaf(bf2f_lo(av), sc_s[c0], sh_s[c0]), 0.f), bf2f_lo(xv));
  float x1 = fmaf(w, fmaxf(fmaf(bf2f_hi(av), sc_s[c1], sh_s[c1]), 0.f), bf2f_hi(xv));
  float a00 = x0 * fcW[c0 * 2 + 0] + x1 * fcW[c1 * 2 + 0];
  float a01 = x0 * fcW[c0 * 2 + 1] + x1 * fcW[c1 * 2 + 1];
  float a10 = x0 * fcW[(128 + c0) * 2 + 0] + x1 * fcW[(128 + c1) * 2 + 0];
  float a11 = x0 * fcW[(128 + c0) * 2 + 1] + x1 * fcW[(128 + c1) * 2 + 1];
#pragma unroll
  for (int off = 32; off; off >>= 1) {
    a00 += __shfl_down(a00, off);
    a01 += __shfl_down(a01, off);
    a10 += __shfl_down(a10, off);
    a11 += __shfl_down(a11, off);
  }
  if (lane == 0) *(float4*)(y + (size_t)r * 4) = make_float4(a00, a01, a10, a11);
}

__global__ void edge_out_kernel(const float* __restrict__ y, const int* __restrict__ eo,
                                const float* __restrict__ fcb, float* __restrict__ out, int m) {
  int j = blockIdx.x * blockDim.x + threadIdx.x;
  if (j >= m) return;
  int a = eo[j], b = eo[m + j];
  float4 ya = *(const float4*)(y + (size_t)a * 4);
  float4 yb = *(const float4*)(y + (size_t)b * 4);
  out[(size_t)j * 2 + 0] = ya.x + yb.z + fcb[0];
  out[(size_t)j * 2 + 1] = ya.y + yb.w + fcb[1];
}

// ---------------------------------------------------------------------------

extern "C" void kernel_launch(void* const* d_in, const int* in_sizes, int n_in,
                              void* d_out, int out_size, void* d_ws, size_t ws_size,
                              hipStream_t stream) {
  const float* x     = (const float*)d_in[0];
  const int*   ei    = (const int*)d_in[1];
  const int*   eo    = (const int*)d_in[2];
  const float* embW  = (const float*)d_in[3];
  const float* embB  = (const float*)d_in[4];
  const float* convW = (const float*)d_in[5];
  const float* gamma = (const float*)d_in[7];
  const float* beta  = (const float*)d_in[8];
  const float* lw    = (const float*)d_in[9];
  const float* fcW   = (const float*)d_in[10];
  const float* fcb   = (const float*)d_in[11];
  float* out = (float*)d_out;

  const int n = in_sizes[0] / 16;          // 100000
  const int e = in_sizes[1] / 2;           // 1600000
  const int m = in_sizes[2] / 2;           // 400000
  const int L = in_sizes[5] / (128 * 128); // 6

  const int T   = e + n;                   // total edges incl self loops
  const int EB  = (T + NW - 1) / NW;       // edges per wave target
  const int nbk = (n + BKT - 1) / BKT;     // 782 buckets

  const int* esrc = ei;
  const int* edst = ei + e;

  char* wsp = (char*)d_ws;
  size_t off = 0;
  auto take = [&](size_t bytes) -> void* {
    void* p = wsp + off;
    off = (off + bytes + 255) & ~(size_t)255;
    return p;
  };
  int*            bcnt     = (int*)take((size_t)(nbk + 1) * 4);
  int*            bbase    = (int*)take((size_t)(nbk + 1) * 4);
  int*            bfill    = (int*)take((size_t)(nbk + 1) * 4);
  int*            rs       = (int*)take((size_t)(n + 1) * 4);
  float*          dis      = (float*)take((size_t)n * 4);
  float*          hscale   = (float*)take((size_t)n * 4);
  float*          wsm      = (float*)take(64 * 4);
  float*          stats    = (float*)take((size_t)L * 8 * 256 * 4);
  int*            A        = (int*)take((size_t)(NW + 1) * 4);
  unsigned*       ebuf     = (unsigned*)take((size_t)T * 4);  // packed bucketed records
  int2*           ebuf2    = (int2*)take((size_t)T * 8);      // sorted (src,dst)
  int2*           esn      = (int2*)take((size_t)T * 8);      // static (src, norm|flag)
  unsigned short* xe16     = (unsigned short*)take((size_t)n * 128 * 2);
  unsigned char*  hq       = (unsigned char*)take((size_t)n * 128);
  unsigned*       aggbf    = (unsigned*)take((size_t)n * 64 * 4);
  unsigned short* Wt       = (unsigned short*)take((size_t)L * 128 * 128 * 2);
  float*          y        = (float*)take((size_t)n * 4 * 4);
  if (off > ws_size || nbk > 1024) return;

  // --- preprocessing: radix sort by dst ---
  hipMemsetAsync(bcnt, 0, (size_t)(nbk + 1) * 4, stream);
  hipMemsetAsync(stats, 0, (size_t)L * 8 * 256 * 4, stream);
  hist_bucket_kernel<<<512, 256, 0, stream>>>(edst, bcnt, e, n, nbk);
  scan_buckets_kernel<<<1, 1024, 0, stream>>>(bcnt, bbase, nbk, T);
  hipMemcpyAsync(bfill, bbase, (size_t)nbk * 4, hipMemcpyDeviceToDevice, stream);
  scatter_bucket_kernel<<<512, 256, 0, stream>>>(esrc, edst, bfill, ebuf, e, n, nbk);
  sort_bucket_kernel<<<nbk, 256, 0, stream>>>(bbase, ebuf, ebuf2, rs, dis, n, T);
  norm_kernel<<<(T + 255) / 256, 256, 0, stream>>>(ebuf2, dis, esn, T);
  const int wbBlocks = (NW + 256) / 256;
  const int wtBlocks = (L * 16384 + 255) / 256;
  misc_kernel<<<wbBlocks + wtBlocks + 1, 256, 0, stream>>>(
      rs, A, n, NW, EB, wbBlocks, convW, Wt, L * 16384, wtBlocks, lw, wsm, L);

  // --- embed (bf16 xe) ---
  embed_kernel<<<1024, 256, 0, stream>>>(x, embW, embB, xe16, n);

  // --- 6 GCN layers (conv_b dropped: cancels under BN) ---
  const int ntiles = (n + 63) >> 6;
  const int gemm_grid = (ntiles + 1) / 2;   // exactly <=2 tiles per block
  for (int i = 0; i < L; ++i) {
    if (i == 0) {
      gemm_fused_kernel<false><<<gemm_grid, 256, 0, stream>>>(
          nullptr, nullptr, nullptr, nullptr, wsm, 0, (unsigned*)xe16,
          Wt, hq, hscale, n);
    } else {
      gemm_fused_kernel<true><<<gemm_grid, 256, 0, stream>>>(
          aggbf, stats + (size_t)(i - 1) * 2048,
          gamma + (size_t)(i - 1) * 128, beta + (size_t)(i - 1) * 128, wsm, i - 1,
          (unsigned*)xe16, Wt + (size_t)i * 16384, hq, hscale, n);
    }
    spmm_kernel<<<NW / 4, 256, 0, stream>>>(rs, A, esn, hscale, hq,
                                            aggbf, stats + (size_t)i * 2048, n);
  }

  // --- final FC (fused BN of layer L-1) ---
  fc_node_kernel<<<(n + 3) / 4, 256, 0, stream>>>(
      aggbf, stats + (size_t)(L - 1) * 2048,
      gamma + (size_t)(L - 1) * 128, beta + (size_t)(L - 1) * 128, wsm, L - 1,
      (const unsigned*)xe16, fcW, y, n);
  edge_out_kernel<<<(m + 255) / 256, 256, 0, stream>>>(y, eo, fcb, out, m);
}